// Round 8
// baseline (104.925 us; speedup 1.0000x reference)
//
#include <hip/hip_runtime.h>
#include <hip/hip_bf16.h>

#define T_SEQ 2048
#define BATCH 2
#define DMODEL 512
#define NHEAD 8
#define DHEAD 64
#define DVAL 64
#define BH 16
#define CHUNK 64
#define NCHUNK 32
#define MROWS 4096   // BATCH*T_SEQ

typedef __bf16 bf16;
typedef __bf16 bf16x8 __attribute__((ext_vector_type(8)));
typedef __bf16 bf16x4 __attribute__((ext_vector_type(4)));
typedef float f32x4 __attribute__((ext_vector_type(4)));

__device__ inline void gload_lds16(const bf16* g, bf16* l) {
  __builtin_amdgcn_global_load_lds((const __attribute__((address_space(1))) void*)g,
                                   (__attribute__((address_space(3))) void*)l, 16, 0, 0);
}

// XOR-swizzled slot offset (elements) for 64-col bf16 LDS tiles.
__device__ inline int sw_t(int row, int g) {
  return ((g ^ (row & 7) ^ (row >> 3)) << 3);
}

// ---------------- kernel 0: fp32 -> bf16 conversion (vectorized) ----------------
__global__ __launch_bounds__(256) void k_convert(const float* __restrict__ x,
                          const float* __restrict__ wq,
                          const float* __restrict__ wk,
                          const float* __restrict__ wv,
                          const float* __restrict__ wo,
                          bf16* __restrict__ x_bf,
                          bf16* __restrict__ wqkv_bf,
                          bf16* __restrict__ wo_bf) {
  const int W = DMODEL * DMODEL;           // 262144
  int i = blockIdx.x * 256 + threadIdx.x;  // 0..524287 (grid 2048)
  {
    f32x4 v = ((const f32x4*)x)[i];
    bf16x4 o; o[0] = (bf16)v[0]; o[1] = (bf16)v[1]; o[2] = (bf16)v[2]; o[3] = (bf16)v[3];
    *(bf16x4*)(x_bf + (size_t)i * 4) = o;
  }
  if (i < W / 4) {
    f32x4 a = ((const f32x4*)wq)[i];
    f32x4 b = ((const f32x4*)wk)[i];
    f32x4 c = ((const f32x4*)wv)[i];
    f32x4 d = ((const f32x4*)wo)[i];
    bf16x4 oa, ob, oc, od;
#pragma unroll
    for (int u = 0; u < 4; u++) { oa[u] = (bf16)a[u]; ob[u] = (bf16)b[u]; oc[u] = (bf16)c[u]; od[u] = (bf16)d[u]; }
    *(bf16x4*)(wqkv_bf + (size_t)i * 4) = oa;
    *(bf16x4*)(wqkv_bf + W + (size_t)i * 4) = ob;
    *(bf16x4*)(wqkv_bf + 2 * W + (size_t)i * 4) = oc;
    *(bf16x4*)(wo_bf + (size_t)i * 4) = od;
  }
}

// ---------------- QKV GEMM: 128x128 tile, BK=64, double-buffered 1-barrier/step ----------------
// 2x2 wave grid, each wave owns a 64x64 quadrant: 32 MFMA + 16 ds_read per K-step
// (~400 cy compute) vs ~500 cy load latency -> 1-deep prefetch now actually covers.
// Grid (32,12)=384 blocks; LDS 2x32KB=64KB -> 2 blocks/CU.
__global__ __launch_bounds__(256) void k_gemm_qkv(const bf16* __restrict__ A,
                                                  const bf16* __restrict__ B,
                                                  bf16* __restrict__ Q,
                                                  bf16* __restrict__ K,
                                                  bf16* __restrict__ V) {
  __shared__ bf16 sh[32768];   // 2 x (As 8192 + Bs 8192) elems = 64 KB
  const int tid = threadIdx.x;
  const int wvi = tid >> 6, lane = tid & 63;
  const int c = lane & 15, quad = lane >> 4;
  const int wr = wvi >> 1, wc = wvi & 1;           // 2x2 wave grid
  const int m_tile = blockIdx.x * 128, n_tile = blockIdx.y * 128;
  const int r8 = lane >> 3, gp = lane & 7;
  const bf16* Abase = A + (size_t)m_tile * DMODEL;
  const bf16* Bbase = B + (size_t)n_tile * DMODEL;

  auto STAGE = [&](int buf, int k0) {
    bf16* As = sh + buf * 16384;
    bf16* Bs = As + 8192;
#pragma unroll
    for (int r = 0; r < 4; r++) {          // A: 128 rows = 16 groups of 8
      int t8 = wvi * 4 + r;
      const bf16* ga = Abase + (size_t)(t8 * 8 + r8) * DMODEL + k0 + ((gp ^ r8) << 3);
      gload_lds16(ga, As + t8 * 8 * 64);
    }
#pragma unroll
    for (int r = 0; r < 4; r++) {          // B: 128 rows = 16 groups of 8
      int t8 = wvi * 4 + r;
      const bf16* gb = Bbase + (size_t)(t8 * 8 + r8) * DMODEL + k0 + ((gp ^ r8) << 3);
      gload_lds16(gb, Bs + t8 * 8 * 64);
    }
  };

  f32x4 acc[4][4] = {};

  STAGE(0, 0);
  __syncthreads();
  int cur = 0;
  for (int k0 = 0; k0 < DMODEL; k0 += 64) {
    if (k0 + 64 < DMODEL) STAGE(cur ^ 1, k0 + 64);   // issue next-step loads early
    bf16* As = sh + cur * 16384;
    bf16* Bs = As + 8192;
#pragma unroll
    for (int ks = 0; ks < 2; ks++) {
      bf16x8 af[4], bfr[4];
#pragma unroll
      for (int i = 0; i < 4; i++) {
        int ar = wr * 64 + i * 16 + c;
        af[i] = *(const bf16x8*)(As + ar * 64 + (((ks * 4 + quad) ^ (c & 7)) << 3));
      }
#pragma unroll
      for (int j = 0; j < 4; j++) {
        int br = wc * 64 + j * 16 + c;
        bfr[j] = *(const bf16x8*)(Bs + br * 64 + (((ks * 4 + quad) ^ (c & 7)) << 3));
      }
#pragma unroll
      for (int i = 0; i < 4; i++)
#pragma unroll
        for (int j = 0; j < 4; j++)
          acc[i][j] = __builtin_amdgcn_mfma_f32_16x16x32_bf16(af[i], bfr[j], acc[i][j], 0, 0, 0);
    }
    __syncthreads();   // drains next-stage vmcnt after compute; next buf ready
    cur ^= 1;
  }

  // bf16 repack: 128x128 tile, stride 132 (33 KB overlays the dbuf area)
  const bool is_qk = (n_tile < 1024);   // uniform per block (tiles don't straddle Q/K/V)
#pragma unroll
  for (int i = 0; i < 4; i++)
#pragma unroll
    for (int j = 0; j < 4; j++)
#pragma unroll
      for (int r = 0; r < 4; r++) {
        int row = wr * 64 + i * 16 + quad * 4 + r;
        int col = wc * 64 + j * 16 + c;
        float v = acc[i][j][r];
        if (is_qk) v = (v > 0.f) ? (v + 1.f) : __expf(v);  // phi = elu+1
        sh[row * 132 + col] = (bf16)v;
      }
  __syncthreads();
  bf16* dst = (n_tile < 512) ? Q : ((n_tile < 1024) ? K : V);
  int nb = n_tile & 511;
#pragma unroll
  for (int q = 0; q < 8; q++) {
    int row = q * 16 + (tid >> 4);
    int col0 = (tid & 15) * 8;
    bf16x8 v8 = *(const bf16x8*)(sh + row * 132 + col0);
    *(bf16x8*)(dst + (size_t)(m_tile + row) * 512 + nb + col0) = v8;
  }
}

// ---------------- Out GEMM: 64x64 tile, BK=64, double-buffered 1-barrier/step ----------------
__global__ __launch_bounds__(256) void k_gemm_out(const bf16* __restrict__ A,
                                                  const bf16* __restrict__ B,
                                                  float* __restrict__ out) {
  __shared__ bf16 sh[16384];   // 2 x (As 4096 + Bs 4096) = 32 KB; 2 blocks/CU = 64 KB
  const int tid = threadIdx.x;
  const int wvi = tid >> 6, lane = tid & 63;
  const int c = lane & 15, quad = lane >> 4;
  const int m_tile = blockIdx.x * 64, n_tile = blockIdx.y * 64;
  const int r8 = lane >> 3, gp = lane & 7;
  const bf16* Abase = A + (size_t)m_tile * DMODEL;
  const bf16* Bbase = B + (size_t)n_tile * DMODEL;
  const int wn = wvi * 16;

  auto STAGE = [&](int buf, int k0) {
    bf16* As = sh + buf * 8192;
    bf16* Bs = As + 4096;
#pragma unroll
    for (int r = 0; r < 2; r++) {           // A: 64 rows = 8 groups of 8
      int t8 = wvi * 2 + r;
      const bf16* ga = Abase + (size_t)(t8 * 8 + r8) * DMODEL + k0 + ((gp ^ r8) << 3);
      gload_lds16(ga, As + t8 * 8 * 64);
    }
#pragma unroll
    for (int r = 0; r < 2; r++) {           // B: 64 rows = 8 groups of 8
      int t8 = wvi * 2 + r;
      const bf16* gb = Bbase + (size_t)(t8 * 8 + r8) * DMODEL + k0 + ((gp ^ r8) << 3);
      gload_lds16(gb, Bs + t8 * 8 * 64);
    }
  };

  f32x4 acc[4] = {};

  STAGE(0, 0);
  __syncthreads();
  int cur = 0;
  for (int k0 = 0; k0 < DMODEL; k0 += 64) {
    if (k0 + 64 < DMODEL) STAGE(cur ^ 1, k0 + 64);
    bf16* As = sh + cur * 8192;
    bf16* Bs = As + 4096;
#pragma unroll
    for (int ks = 0; ks < 2; ks++) {
      bf16x8 af[4], bfr;
#pragma unroll
      for (int i = 0; i < 4; i++)
        af[i] = *(const bf16x8*)(As + (i * 16 + c) * 64 + (((ks * 4 + quad) ^ (c & 7)) << 3));
      bfr = *(const bf16x8*)(Bs + (wn + c) * 64 + (((ks * 4 + quad) ^ (c & 7)) << 3));
#pragma unroll
      for (int i = 0; i < 4; i++)
        acc[i] = __builtin_amdgcn_mfma_f32_16x16x32_bf16(af[i], bfr, acc[i], 0, 0, 0);
    }
    __syncthreads();
    cur ^= 1;
  }

  // fp32 repack in two 32-row half passes (stride 68 floats, 8.7 KB)
  float* shf = (float*)sh;
#pragma unroll
  for (int p = 0; p < 2; p++) {
    __syncthreads();
#pragma unroll
    for (int i2 = 0; i2 < 2; i2++) {         // i-frags 2p, 2p+1
      int i = 2 * p + i2;
#pragma unroll
      for (int r = 0; r < 4; r++)
        shf[(i2 * 16 + quad * 4 + r) * 68 + wn + c] = acc[i][r];
    }
    __syncthreads();
    int row = tid >> 3, col0 = (tid & 7) * 8;
#pragma unroll
    for (int q4 = 0; q4 < 2; q4++) {
      f32x4 v4 = *(const f32x4*)(shf + row * 68 + col0 + q4 * 4);
      *(f32x4*)(out + (size_t)(m_tile + p * 32 + row) * 512 + n_tile + col0 + q4 * 4) = v4;
    }
  }
}

// ---------------- kernel 2: per-chunk S^T_c = V^T K (MFMA) + z_c ----------------
// State stored in register-layout slot order (slot s=f*4+r at op+tid*16+s).
__global__ __launch_bounds__(256) void k_state(const bf16* __restrict__ K,
                                               const bf16* __restrict__ V,
                                               bf16* __restrict__ KVs,
                                               float* __restrict__ zsum) {
  __shared__ bf16 Kt[4096];   // Kt[i][t] swizzled
  __shared__ bf16 Vt[4096];   // Vt[j][t] swizzled
  int chunk = blockIdx.x, bh = blockIdx.y;
  int b = bh >> 3, h = bh & 7;
  int tid = threadIdx.x, lane = tid & 63, wvi = tid >> 6;
  int rowbase = b * T_SEQ + chunk * CHUNK;

#pragma unroll
  for (int p = 0; p < 2; p++) {
    int r = p * 32 + (tid >> 3);
    int j0 = (tid & 7) * 8;
    bf16x8 kk  = *(const bf16x8*)(K + (size_t)(rowbase + r) * 512 + h * 64 + j0);
    bf16x8 vvv = *(const bf16x8*)(V + (size_t)(rowbase + r) * 512 + h * 64 + j0);
#pragma unroll
    for (int u = 0; u < 8; u++) {
      int row = j0 + u;
      Kt[row * 64 + sw_t(row, r >> 3) + (r & 7)] = kk[u];
      Vt[row * 64 + sw_t(row, r >> 3) + (r & 7)] = vvv[u];
    }
  }
  __syncthreads();

  int c = lane & 15, quad = lane >> 4;
  f32x4 acc[4] = {};
#pragma unroll
  for (int ks = 0; ks < 2; ks++) {
    int ar = wvi * 16 + c;
    bf16x8 a = *(const bf16x8*)(Vt + ar * 64 + sw_t(ar, ks * 4 + quad));
#pragma unroll
    for (int f = 0; f < 4; f++) {
      int br = f * 16 + c;
      bf16x8 bb = *(const bf16x8*)(Kt + br * 64 + sw_t(br, ks * 4 + quad));
      acc[f] = __builtin_amdgcn_mfma_f32_16x16x32_bf16(a, bb, acc[f], 0, 0, 0);
    }
  }
  bf16* op = KVs + ((size_t)(bh * NCHUNK + chunk) << 12);
  bf16x8 lo, hi;
#pragma unroll
  for (int u = 0; u < 8; u++) {
    lo[u] = (bf16)acc[u >> 2][u & 3];
    hi[u] = (bf16)acc[2 + (u >> 2)][u & 3];
  }
  *(bf16x8*)(op + tid * 16) = lo;
  *(bf16x8*)(op + tid * 16 + 8) = hi;

  if (tid < 64) {
    float s = 0.f;
#pragma unroll
    for (int g = 0; g < 8; g++) {
      bf16x8 kr = *(const bf16x8*)(Kt + tid * 64 + sw_t(tid, g));
#pragma unroll
      for (int u = 0; u < 8; u++) s += (float)kr[u];
    }
    zsum[(size_t)(bh * NCHUNK + chunk) * 64 + tid] = s;
  }
}

// ---------------- kernel 3: fused prefix + intra-chunk attention (MFMA) ----------------
// 1-D grid of 512, balance-remapped (CU k hosts chunks c and 31-c).
__global__ __launch_bounds__(256) void k_attn(const bf16* __restrict__ Q,
                                              const bf16* __restrict__ K,
                                              const bf16* __restrict__ V,
                                              const bf16* __restrict__ KVs,
                                              const float* __restrict__ zsum,
                                              bf16* __restrict__ O) {
  __shared__ bf16 SH[20480];
  bf16* Qs   = SH;            // 4096, async-staged row layout
  bf16* Ks   = SH + 4096;     // 4096
  bf16* Vt   = SH + 8192;     // 4096, transposed sw_t
  bf16* Asm  = SH + 12288;    // 4096, attention matrix
  bf16* Spre = SH + 16384;    // 4096, S^T_prefix
  __shared__ float zp4[4][64];
  __shared__ float zpre[64], rsum[64], den[64];

  // balance remap: half 0 -> (chunk=k&31, bh=k>>5); half 1 -> (31-(k&31), 8+(k>>5))
  int bid = blockIdx.x;
  int kk5 = bid & 255, half = bid >> 8;
  int chunk = half ? (31 - (kk5 & 31)) : (kk5 & 31);
  int bh = (kk5 >> 5) + (half << 3);

  int b = bh >> 3, h = bh & 7;
  int tid = threadIdx.x, lane = tid & 63, wvi = tid >> 6;
  int c = lane & 15, quad = lane >> 4;
  int rowbase = b * T_SEQ + chunk * CHUNK;

  // async stage Qs, Ks
#pragma unroll
  for (int p = 0; p < 2; p++) {
    int rbase = p * 32 + wvi * 8;
    int r8 = lane >> 3, gp = lane & 7;
    const bf16* gq = Q + (size_t)(rowbase + rbase + r8) * 512 + h * 64 + ((gp ^ r8) << 3);
    const bf16* gk = K + (size_t)(rowbase + rbase + r8) * 512 + h * 64 + ((gp ^ r8) << 3);
    gload_lds16(gq, Qs + rbase * 64);
    gload_lds16(gk, Ks + rbase * 64);
  }

  // V load + transpose into Vt
#pragma unroll
  for (int p = 0; p < 2; p++) {
    int r = p * 32 + (tid >> 3);
    int j0 = (tid & 7) * 8;
    bf16x8 vvv = *(const bf16x8*)(V + (size_t)(rowbase + r) * 512 + h * 64 + j0);
#pragma unroll
    for (int u = 0; u < 8; u++) {
      int row = j0 + u;
      Vt[row * 64 + sw_t(row, r >> 3) + (r & 7)] = vvv[u];
    }
  }

  // prefix of chunk states, software-pipelined batches of 8 (order-preserving)
  {
    float accp[16];
#pragma unroll
    for (int u = 0; u < 16; u++) accp[u] = 0.f;
    const bf16* base = KVs + ((size_t)(bh * NCHUNK) << 12) + tid * 16;
    for (int cc0 = 0; cc0 < chunk; cc0 += 8) {
      bf16x8 ba[8], bb[8];
#pragma unroll
      for (int u = 0; u < 8; u++) {
        if (cc0 + u < chunk) {
          const bf16* pp = base + ((size_t)(cc0 + u) << 12);
          ba[u] = *(const bf16x8*)pp;
          bb[u] = *(const bf16x8*)(pp + 8);
        }
      }
#pragma unroll
      for (int u = 0; u < 8; u++) {
        if (cc0 + u < chunk) {
#pragma unroll
          for (int v = 0; v < 8; v++) { accp[v] += (float)ba[u][v]; accp[8 + v] += (float)bb[u][v]; }
        }
      }
    }
#pragma unroll
    for (int s = 0; s < 16; s++) {
      int rowp = wvi * 16 + quad * 4 + (s & 3);
      int colp = (s >> 2) * 16 + c;
      Spre[rowp * 64 + sw_t(rowp, colp >> 3) + (colp & 7)] = (bf16)accp[s];
    }
  }
  // z prefix partials (per wave) — batched loads (cc-ascending sum order preserved)
  {
    int i = tid & 63, qq = tid >> 6;
    float zv[8];
#pragma unroll
    for (int u = 0; u < 8; u++) {
      int cc = qq + u * 4;
      zv[u] = (cc < chunk) ? zsum[(size_t)(bh * NCHUNK + cc) * 64 + i] : 0.f;
    }
    float s = 0.f;
#pragma unroll
    for (int u = 0; u < 8; u++) s += zv[u];
    zp4[qq][i] = s;
  }
  __syncthreads();  // B1: all LDS staged
  if (tid < 64) zpre[tid] = zp4[0][tid] + zp4[1][tid] + zp4[2][tid] + zp4[3][tid];

  // QK^T
  f32x4 sacc[4] = {};
#pragma unroll
  for (int ks = 0; ks < 2; ks++) {
    int ar = 16 * wvi + c;
    bf16x8 a = *(const bf16x8*)(Qs + ar * 64 + (((ks * 4 + quad) ^ (c & 7)) << 3));
#pragma unroll
    for (int j = 0; j < 4; j++) {
      int br = 16 * j + c;
      bf16x8 bb = *(const bf16x8*)(Ks + br * 64 + (((ks * 4 + quad) ^ (c & 7)) << 3));
      sacc[j] = __builtin_amdgcn_mfma_f32_16x16x32_bf16(a, bb, sacc[j], 0, 0, 0);
    }
  }

  // mask, rowsum, write Asm
  float rs[4] = {0.f, 0.f, 0.f, 0.f};
#pragma unroll
  for (int j = 0; j < 4; j++) {
#pragma unroll
    for (int r = 0; r < 4; r++) {
      int t = 16 * wvi + quad * 4 + r, s = 16 * j + c;
      float v = (s <= t) ? sacc[j][r] : 0.f;
      rs[r] += v;
      Asm[t * 64 + sw_t(t, s >> 3) + (s & 7)] = (bf16)v;
    }
  }
#pragma unroll
  for (int r = 0; r < 4; r++) {
    float v = rs[r];
    v += __shfl_xor(v, 1); v += __shfl_xor(v, 2);
    v += __shfl_xor(v, 4); v += __shfl_xor(v, 8);
    if (c == 0) rsum[16 * wvi + quad * 4 + r] = v;
  }
  __syncthreads();  // B2: Asm, rsum, zpre visible

  // den[t] = max(rowsum + Q[t].z_pre, 1e-6)
  if (tid < 64) {
    float s = rsum[tid];
    int t7 = tid & 7;
#pragma unroll
    for (int kg = 0; kg < 8; kg++) {
      bf16x8 qv = *(const bf16x8*)(Qs + tid * 64 + ((kg ^ t7) << 3));
#pragma unroll
      for (int u = 0; u < 8; u++) s += (float)qv[u] * zpre[kg * 8 + u];
    }
    den[tid] = fmaxf(s, 1e-6f);
  }

  // O = Q.S_pre + A.V
  f32x4 oacc[4] = {};
#pragma unroll
  for (int ks = 0; ks < 2; ks++) {
    int ar = 16 * wvi + c;
    bf16x8 aq = *(const bf16x8*)(Qs + ar * 64 + (((ks * 4 + quad) ^ (c & 7)) << 3));
    bf16x8 aa = *(const bf16x8*)(Asm + ar * 64 + sw_t(ar, ks * 4 + quad));
#pragma unroll
    for (int j = 0; j < 4; j++) {
      int br = 16 * j + c;
      bf16x8 bs = *(const bf16x8*)(Spre + br * 64 + sw_t(br, ks * 4 + quad));
      bf16x8 bv = *(const bf16x8*)(Vt + br * 64 + sw_t(br, ks * 4 + quad));
      oacc[j] = __builtin_amdgcn_mfma_f32_16x16x32_bf16(aq, bs, oacc[j], 0, 0, 0);
      oacc[j] = __builtin_amdgcn_mfma_f32_16x16x32_bf16(aa, bv, oacc[j], 0, 0, 0);
    }
  }
  __syncthreads();  // B3: den visible; Qs/Ks region dead -> repack scratch

  // O repack (stride 76) + vector store
  {
    bf16* shr = SH;   // 64*76 = 4864 elems, overlays Qs/Ks
#pragma unroll
    for (int r = 0; r < 4; r++) {
      int t = 16 * wvi + quad * 4 + r;
      float rd = 1.f / den[t];
#pragma unroll
      for (int j = 0; j < 4; j++)
        shr[t * 76 + 16 * j + c] = (bf16)(oacc[j][r] * rd);
    }
    __syncthreads();
    int row = tid >> 2, col0 = (tid & 3) * 16;
    bf16x8 v0 = *(const bf16x8*)(shr + row * 76 + col0);
    bf16x8 v1 = *(const bf16x8*)(shr + row * 76 + col0 + 8);
    bf16* od = O + (size_t)(rowbase + row) * 512 + h * 64 + col0;
    *(bf16x8*)od = v0;
    *(bf16x8*)(od + 8) = v1;
  }
}

extern "C" void kernel_launch(void* const* d_in, const int* in_sizes, int n_in,
                              void* d_out, int out_size, void* d_ws, size_t ws_size,
                              hipStream_t stream) {
  const float* x  = (const float*)d_in[0];
  const float* wq = (const float*)d_in[1];
  const float* wk = (const float*)d_in[2];
  const float* wv = (const float*)d_in[3];
  const float* wo = (const float*)d_in[4];
  float* out = (float*)d_out;

  char* p = (char*)d_ws;
  bf16* x_bf   = (bf16*)p; p += (size_t)MROWS * DMODEL * 2;
  bf16* wqkv_b = (bf16*)p; p += (size_t)3 * DMODEL * DMODEL * 2;
  bf16* wo_b   = (bf16*)p; p += (size_t)DMODEL * DMODEL * 2;
  bf16* Qb     = (bf16*)p; p += (size_t)MROWS * 512 * 2;
  bf16* Kb     = (bf16*)p; p += (size_t)MROWS * 512 * 2;
  bf16* Vb     = (bf16*)p; p += (size_t)MROWS * 512 * 2;
  bf16* Ob     = (bf16*)p; p += (size_t)MROWS * 512 * 2;
  bf16* KVs    = (bf16*)p; p += (size_t)BH * NCHUNK * DHEAD * DVAL * 2;
  float* zs    = (float*)p; p += (size_t)BH * NCHUNK * DHEAD * 4;

  k_convert<<<2048, 256, 0, stream>>>(x, wq, wk, wv, wo, x_bf, wqkv_b, wo_b);
  k_gemm_qkv<<<dim3(MROWS / 128, (3 * DMODEL) / 128), 256, 0, stream>>>(
      x_bf, wqkv_b, Qb, Kb, Vb);
  k_state<<<dim3(NCHUNK, BH), 256, 0, stream>>>(Kb, Vb, KVs, zs);
  k_attn<<<512, 256, 0, stream>>>(Qb, Kb, Vb, KVs, zs, Ob);
  k_gemm_out<<<dim3(MROWS / 64, DMODEL / 64), 256, 0, stream>>>(Ob, wo_b, out);
}

// Round 9
// 103.328 us; speedup vs baseline: 1.0155x; 1.0155x over previous
//
#include <hip/hip_runtime.h>
#include <hip/hip_bf16.h>

#define T_SEQ 2048
#define BATCH 2
#define DMODEL 512
#define NHEAD 8
#define DHEAD 64
#define DVAL 64
#define BH 16
#define CHUNK 64
#define NCHUNK 32
#define MROWS 4096   // BATCH*T_SEQ

typedef __bf16 bf16;
typedef __bf16 bf16x8 __attribute__((ext_vector_type(8)));
typedef __bf16 bf16x4 __attribute__((ext_vector_type(4)));
typedef float f32x4 __attribute__((ext_vector_type(4)));

__device__ inline void gload_lds16(const bf16* g, bf16* l) {
  __builtin_amdgcn_global_load_lds((const __attribute__((address_space(1))) void*)g,
                                   (__attribute__((address_space(3))) void*)l, 16, 0, 0);
}

// XOR-swizzled slot offset (elements) for 64-col bf16 LDS tiles.
__device__ inline int sw_t(int row, int g) {
  return ((g ^ (row & 7) ^ (row >> 3)) << 3);
}

// ---------------- kernel 0: fp32 -> bf16 weight conversion (weights only) ----------------
// x conversion is fused into k_gemm_qkv's A staging (reads fp32 x directly).
__global__ __launch_bounds__(256) void k_convert(const float* __restrict__ wq,
                          const float* __restrict__ wk,
                          const float* __restrict__ wv,
                          const float* __restrict__ wo,
                          bf16* __restrict__ wqkv_bf,
                          bf16* __restrict__ wo_bf) {
  const int W = DMODEL * DMODEL;           // 262144
  int i = blockIdx.x * 256 + threadIdx.x;  // 0..65535 (grid 256), W/4 elements
  f32x4 a = ((const f32x4*)wq)[i];
  f32x4 b = ((const f32x4*)wk)[i];
  f32x4 c = ((const f32x4*)wv)[i];
  f32x4 d = ((const f32x4*)wo)[i];
  bf16x4 oa, ob, oc, od;
#pragma unroll
  for (int u = 0; u < 4; u++) { oa[u] = (bf16)a[u]; ob[u] = (bf16)b[u]; oc[u] = (bf16)c[u]; od[u] = (bf16)d[u]; }
  *(bf16x4*)(wqkv_bf + (size_t)i * 4) = oa;
  *(bf16x4*)(wqkv_bf + W + (size_t)i * 4) = ob;
  *(bf16x4*)(wqkv_bf + 2 * W + (size_t)i * 4) = oc;
  *(bf16x4*)(wo_bf + (size_t)i * 4) = od;
}

// ---------------- QKV GEMM: 64x128 tile, BK=64, dbuf 1-barrier/step, fp32-A fused cvt ---------
// A is reg-staged from fp32 x (load f32x4 pair -> cvt -> ds_write, same swizzled layout
// and identical bf16 bytes as the old x_bf path); B stays gload_lds from bf16 weights.
// Loads for step k+1 are issued before step k's compute (dbuf hides latency as before).
__global__ __launch_bounds__(256) void k_gemm_qkv(const float* __restrict__ Xf,
                                                  const bf16* __restrict__ B,
                                                  bf16* __restrict__ Q,
                                                  bf16* __restrict__ K,
                                                  bf16* __restrict__ V) {
  __shared__ bf16 sh[24576];   // 2 x (As 4096 + Bs 8192) = 48 KB; 3 blocks/CU = 144 KB
  const int tid = threadIdx.x;
  const int wvi = tid >> 6, lane = tid & 63;
  const int c = lane & 15, quad = lane >> 4;
  const int m_tile = blockIdx.x * 64, n_tile = blockIdx.y * 128;
  const int r8 = lane >> 3, gp = lane & 7;
  const bf16* Bbase = B + (size_t)n_tile * DMODEL;
  const int wn = wvi * 32;

  f32x4 areg[2][2];   // staged fp32 A data (2 row-groups x 8 floats), static-indexed

  auto ALOAD = [&](int k0) {
#pragma unroll
    for (int r = 0; r < 2; r++) {
      int t8 = wvi * 2 + r;
      const float* ga = Xf + (size_t)(m_tile + t8 * 8 + r8) * DMODEL + k0 + ((gp ^ r8) << 3);
      areg[r][0] = *(const f32x4*)ga;
      areg[r][1] = *(const f32x4*)(ga + 4);
    }
  };
  auto AWRITE = [&](int buf) {
    bf16* As = sh + buf * 12288;
#pragma unroll
    for (int r = 0; r < 2; r++) {
      int t8 = wvi * 2 + r;
      bf16x8 o;
#pragma unroll
      for (int u = 0; u < 4; u++) { o[u] = (bf16)areg[r][0][u]; o[4 + u] = (bf16)areg[r][1][u]; }
      *(bf16x8*)(As + t8 * 8 * 64 + lane * 8) = o;   // matches gload_lds lane-linear dest
    }
  };
  auto BSTAGE = [&](int buf, int k0) {
    bf16* Bs = sh + buf * 12288 + 4096;
#pragma unroll
    for (int r = 0; r < 4; r++) {
      int t8 = wvi * 4 + r;
      const bf16* gb = Bbase + (size_t)(t8 * 8 + r8) * DMODEL + k0 + ((gp ^ r8) << 3);
      gload_lds16(gb, Bs + t8 * 8 * 64);
    }
  };

  f32x4 acc[4][2] = {};

  ALOAD(0);
  BSTAGE(0, 0);
  AWRITE(0);
  __syncthreads();
  int cur = 0;
  for (int k0 = 0; k0 < DMODEL; k0 += 64) {
    const bool more = (k0 + 64 < DMODEL);
    if (more) { ALOAD(k0 + 64); BSTAGE(cur ^ 1, k0 + 64); }   // issue next-step loads early
    bf16* As = sh + cur * 12288;
    bf16* Bs = As + 4096;
#pragma unroll
    for (int ks = 0; ks < 2; ks++) {
      bf16x8 af[4], bfr[2];
#pragma unroll
      for (int i = 0; i < 4; i++)
        af[i] = *(const bf16x8*)(As + (i * 16 + c) * 64 + (((ks * 4 + quad) ^ (c & 7)) << 3));
#pragma unroll
      for (int j = 0; j < 2; j++)
        bfr[j] = *(const bf16x8*)(Bs + (wn + j * 16 + c) * 64 + (((ks * 4 + quad) ^ (c & 7)) << 3));
#pragma unroll
      for (int i = 0; i < 4; i++)
#pragma unroll
        for (int j = 0; j < 2; j++)
          acc[i][j] = __builtin_amdgcn_mfma_f32_16x16x32_bf16(af[i], bfr[j], acc[i][j], 0, 0, 0);
    }
    if (more) AWRITE(cur ^ 1);   // cvt + ds_write after compute; cur^1 consumers passed barrier
    __syncthreads();             // drains B gload_lds + A ds_write; next buf ready
    cur ^= 1;
  }

  // bf16 repack: 64x128 tile, stride 132, then 4x b128 stores/thread
  const bool is_qk = (n_tile < 1024);   // uniform per block
#pragma unroll
  for (int i = 0; i < 4; i++)
#pragma unroll
    for (int j = 0; j < 2; j++)
#pragma unroll
      for (int r = 0; r < 4; r++) {
        int row = i * 16 + quad * 4 + r;
        int col = wn + j * 16 + c;
        float v = acc[i][j][r];
        if (is_qk) v = (v > 0.f) ? (v + 1.f) : __expf(v);  // phi = elu+1
        sh[row * 132 + col] = (bf16)v;
      }
  __syncthreads();
  bf16* dst = (n_tile < 512) ? Q : ((n_tile < 1024) ? K : V);
  int nb = n_tile & 511;
#pragma unroll
  for (int q = 0; q < 4; q++) {
    int row = q * 16 + (tid >> 4);
    int col0 = (tid & 15) * 8;
    bf16x8 v8 = *(const bf16x8*)(sh + row * 132 + col0);
    *(bf16x8*)(dst + (size_t)(m_tile + row) * 512 + nb + col0) = v8;
  }
}

// ---------------- Out GEMM: 64x64 tile, BK=64, double-buffered 1-barrier/step ----------------
__global__ __launch_bounds__(256) void k_gemm_out(const bf16* __restrict__ A,
                                                  const bf16* __restrict__ B,
                                                  float* __restrict__ out) {
  __shared__ bf16 sh[16384];   // 2 x (As 4096 + Bs 4096) = 32 KB; 2 blocks/CU = 64 KB
  const int tid = threadIdx.x;
  const int wvi = tid >> 6, lane = tid & 63;
  const int c = lane & 15, quad = lane >> 4;
  const int m_tile = blockIdx.x * 64, n_tile = blockIdx.y * 64;
  const int r8 = lane >> 3, gp = lane & 7;
  const bf16* Abase = A + (size_t)m_tile * DMODEL;
  const bf16* Bbase = B + (size_t)n_tile * DMODEL;
  const int wn = wvi * 16;

  auto STAGE = [&](int buf, int k0) {
    bf16* As = sh + buf * 8192;
    bf16* Bs = As + 4096;
#pragma unroll
    for (int r = 0; r < 2; r++) {           // A: 64 rows = 8 groups of 8
      int t8 = wvi * 2 + r;
      const bf16* ga = Abase + (size_t)(t8 * 8 + r8) * DMODEL + k0 + ((gp ^ r8) << 3);
      gload_lds16(ga, As + t8 * 8 * 64);
    }
#pragma unroll
    for (int r = 0; r < 2; r++) {           // B: 64 rows = 8 groups of 8
      int t8 = wvi * 2 + r;
      const bf16* gb = Bbase + (size_t)(t8 * 8 + r8) * DMODEL + k0 + ((gp ^ r8) << 3);
      gload_lds16(gb, Bs + t8 * 8 * 64);
    }
  };

  f32x4 acc[4] = {};

  STAGE(0, 0);
  __syncthreads();
  int cur = 0;
  for (int k0 = 0; k0 < DMODEL; k0 += 64) {
    if (k0 + 64 < DMODEL) STAGE(cur ^ 1, k0 + 64);
    bf16* As = sh + cur * 8192;
    bf16* Bs = As + 4096;
#pragma unroll
    for (int ks = 0; ks < 2; ks++) {
      bf16x8 af[4], bfr;
#pragma unroll
      for (int i = 0; i < 4; i++)
        af[i] = *(const bf16x8*)(As + (i * 16 + c) * 64 + (((ks * 4 + quad) ^ (c & 7)) << 3));
      bfr = *(const bf16x8*)(Bs + (wn + c) * 64 + (((ks * 4 + quad) ^ (c & 7)) << 3));
#pragma unroll
      for (int i = 0; i < 4; i++)
        acc[i] = __builtin_amdgcn_mfma_f32_16x16x32_bf16(af[i], bfr, acc[i], 0, 0, 0);
    }
    __syncthreads();
    cur ^= 1;
  }

  // fp32 repack in two 32-row half passes (stride 68 floats, 8.7 KB)
  float* shf = (float*)sh;
#pragma unroll
  for (int p = 0; p < 2; p++) {
    __syncthreads();
#pragma unroll
    for (int i2 = 0; i2 < 2; i2++) {         // i-frags 2p, 2p+1
      int i = 2 * p + i2;
#pragma unroll
      for (int r = 0; r < 4; r++)
        shf[(i2 * 16 + quad * 4 + r) * 68 + wn + c] = acc[i][r];
    }
    __syncthreads();
    int row = tid >> 3, col0 = (tid & 7) * 8;
#pragma unroll
    for (int q4 = 0; q4 < 2; q4++) {
      f32x4 v4 = *(const f32x4*)(shf + row * 68 + col0 + q4 * 4);
      *(f32x4*)(out + (size_t)(m_tile + p * 32 + row) * 512 + n_tile + col0 + q4 * 4) = v4;
    }
  }
}

// ---------------- kernel 2: per-chunk S^T_c = V^T K (MFMA) + z_c ----------------
// State stored in register-layout slot order (slot s=f*4+r at op+tid*16+s).
__global__ __launch_bounds__(256) void k_state(const bf16* __restrict__ K,
                                               const bf16* __restrict__ V,
                                               bf16* __restrict__ KVs,
                                               float* __restrict__ zsum) {
  __shared__ bf16 Kt[4096];   // Kt[i][t] swizzled
  __shared__ bf16 Vt[4096];   // Vt[j][t] swizzled
  int chunk = blockIdx.x, bh = blockIdx.y;
  int b = bh >> 3, h = bh & 7;
  int tid = threadIdx.x, lane = tid & 63, wvi = tid >> 6;
  int rowbase = b * T_SEQ + chunk * CHUNK;

#pragma unroll
  for (int p = 0; p < 2; p++) {
    int r = p * 32 + (tid >> 3);
    int j0 = (tid & 7) * 8;
    bf16x8 kk  = *(const bf16x8*)(K + (size_t)(rowbase + r) * 512 + h * 64 + j0);
    bf16x8 vvv = *(const bf16x8*)(V + (size_t)(rowbase + r) * 512 + h * 64 + j0);
#pragma unroll
    for (int u = 0; u < 8; u++) {
      int row = j0 + u;
      Kt[row * 64 + sw_t(row, r >> 3) + (r & 7)] = kk[u];
      Vt[row * 64 + sw_t(row, r >> 3) + (r & 7)] = vvv[u];
    }
  }
  __syncthreads();

  int c = lane & 15, quad = lane >> 4;
  f32x4 acc[4] = {};
#pragma unroll
  for (int ks = 0; ks < 2; ks++) {
    int ar = wvi * 16 + c;
    bf16x8 a = *(const bf16x8*)(Vt + ar * 64 + sw_t(ar, ks * 4 + quad));
#pragma unroll
    for (int f = 0; f < 4; f++) {
      int br = f * 16 + c;
      bf16x8 bb = *(const bf16x8*)(Kt + br * 64 + sw_t(br, ks * 4 + quad));
      acc[f] = __builtin_amdgcn_mfma_f32_16x16x32_bf16(a, bb, acc[f], 0, 0, 0);
    }
  }
  bf16* op = KVs + ((size_t)(bh * NCHUNK + chunk) << 12);
  bf16x8 lo, hi;
#pragma unroll
  for (int u = 0; u < 8; u++) {
    lo[u] = (bf16)acc[u >> 2][u & 3];
    hi[u] = (bf16)acc[2 + (u >> 2)][u & 3];
  }
  *(bf16x8*)(op + tid * 16) = lo;
  *(bf16x8*)(op + tid * 16 + 8) = hi;

  if (tid < 64) {
    float s = 0.f;
#pragma unroll
    for (int g = 0; g < 8; g++) {
      bf16x8 kr = *(const bf16x8*)(Kt + tid * 64 + sw_t(tid, g));
#pragma unroll
      for (int u = 0; u < 8; u++) s += (float)kr[u];
    }
    zsum[(size_t)(bh * NCHUNK + chunk) * 64 + tid] = s;
  }
}

// ---------------- kernel 3: fused prefix + intra-chunk attention (MFMA) ----------------
// 1-D grid of 512, balance-remapped (CU k hosts chunks c and 31-c).
__global__ __launch_bounds__(256) void k_attn(const bf16* __restrict__ Q,
                                              const bf16* __restrict__ K,
                                              const bf16* __restrict__ V,
                                              const bf16* __restrict__ KVs,
                                              const float* __restrict__ zsum,
                                              bf16* __restrict__ O) {
  __shared__ bf16 SH[20480];
  bf16* Qs   = SH;            // 4096, async-staged row layout
  bf16* Ks   = SH + 4096;     // 4096
  bf16* Vt   = SH + 8192;     // 4096, transposed sw_t
  bf16* Asm  = SH + 12288;    // 4096, attention matrix
  bf16* Spre = SH + 16384;    // 4096, S^T_prefix
  __shared__ float zp4[4][64];
  __shared__ float zpre[64], rsum[64], den[64];

  // balance remap: half 0 -> (chunk=k&31, bh=k>>5); half 1 -> (31-(k&31), 8+(k>>5))
  int bid = blockIdx.x;
  int kk5 = bid & 255, half = bid >> 8;
  int chunk = half ? (31 - (kk5 & 31)) : (kk5 & 31);
  int bh = (kk5 >> 5) + (half << 3);

  int b = bh >> 3, h = bh & 7;
  int tid = threadIdx.x, lane = tid & 63, wvi = tid >> 6;
  int c = lane & 15, quad = lane >> 4;
  int rowbase = b * T_SEQ + chunk * CHUNK;

  // async stage Qs, Ks
#pragma unroll
  for (int p = 0; p < 2; p++) {
    int rbase = p * 32 + wvi * 8;
    int r8 = lane >> 3, gp = lane & 7;
    const bf16* gq = Q + (size_t)(rowbase + rbase + r8) * 512 + h * 64 + ((gp ^ r8) << 3);
    const bf16* gk = K + (size_t)(rowbase + rbase + r8) * 512 + h * 64 + ((gp ^ r8) << 3);
    gload_lds16(gq, Qs + rbase * 64);
    gload_lds16(gk, Ks + rbase * 64);
  }

  // V load + transpose into Vt
#pragma unroll
  for (int p = 0; p < 2; p++) {
    int r = p * 32 + (tid >> 3);
    int j0 = (tid & 7) * 8;
    bf16x8 vvv = *(const bf16x8*)(V + (size_t)(rowbase + r) * 512 + h * 64 + j0);
#pragma unroll
    for (int u = 0; u < 8; u++) {
      int row = j0 + u;
      Vt[row * 64 + sw_t(row, r >> 3) + (r & 7)] = vvv[u];
    }
  }

  // prefix of chunk states, software-pipelined batches of 8 (order-preserving)
  {
    float accp[16];
#pragma unroll
    for (int u = 0; u < 16; u++) accp[u] = 0.f;
    const bf16* base = KVs + ((size_t)(bh * NCHUNK) << 12) + tid * 16;
    for (int cc0 = 0; cc0 < chunk; cc0 += 8) {
      bf16x8 ba[8], bb[8];
#pragma unroll
      for (int u = 0; u < 8; u++) {
        if (cc0 + u < chunk) {
          const bf16* pp = base + ((size_t)(cc0 + u) << 12);
          ba[u] = *(const bf16x8*)pp;
          bb[u] = *(const bf16x8*)(pp + 8);
        }
      }
#pragma unroll
      for (int u = 0; u < 8; u++) {
        if (cc0 + u < chunk) {
#pragma unroll
          for (int v = 0; v < 8; v++) { accp[v] += (float)ba[u][v]; accp[8 + v] += (float)bb[u][v]; }
        }
      }
    }
#pragma unroll
    for (int s = 0; s < 16; s++) {
      int rowp = wvi * 16 + quad * 4 + (s & 3);
      int colp = (s >> 2) * 16 + c;
      Spre[rowp * 64 + sw_t(rowp, colp >> 3) + (colp & 7)] = (bf16)accp[s];
    }
  }
  // z prefix partials (per wave) — batched loads (cc-ascending sum order preserved)
  {
    int i = tid & 63, qq = tid >> 6;
    float zv[8];
#pragma unroll
    for (int u = 0; u < 8; u++) {
      int cc = qq + u * 4;
      zv[u] = (cc < chunk) ? zsum[(size_t)(bh * NCHUNK + cc) * 64 + i] : 0.f;
    }
    float s = 0.f;
#pragma unroll
    for (int u = 0; u < 8; u++) s += zv[u];
    zp4[qq][i] = s;
  }
  __syncthreads();  // B1: all LDS staged
  if (tid < 64) zpre[tid] = zp4[0][tid] + zp4[1][tid] + zp4[2][tid] + zp4[3][tid];

  // QK^T
  f32x4 sacc[4] = {};
#pragma unroll
  for (int ks = 0; ks < 2; ks++) {
    int ar = 16 * wvi + c;
    bf16x8 a = *(const bf16x8*)(Qs + ar * 64 + (((ks * 4 + quad) ^ (c & 7)) << 3));
#pragma unroll
    for (int j = 0; j < 4; j++) {
      int br = 16 * j + c;
      bf16x8 bb = *(const bf16x8*)(Ks + br * 64 + (((ks * 4 + quad) ^ (c & 7)) << 3));
      sacc[j] = __builtin_amdgcn_mfma_f32_16x16x32_bf16(a, bb, sacc[j], 0, 0, 0);
    }
  }

  // mask, rowsum, write Asm
  float rs[4] = {0.f, 0.f, 0.f, 0.f};
#pragma unroll
  for (int j = 0; j < 4; j++) {
#pragma unroll
    for (int r = 0; r < 4; r++) {
      int t = 16 * wvi + quad * 4 + r, s = 16 * j + c;
      float v = (s <= t) ? sacc[j][r] : 0.f;
      rs[r] += v;
      Asm[t * 64 + sw_t(t, s >> 3) + (s & 7)] = (bf16)v;
    }
  }
#pragma unroll
  for (int r = 0; r < 4; r++) {
    float v = rs[r];
    v += __shfl_xor(v, 1); v += __shfl_xor(v, 2);
    v += __shfl_xor(v, 4); v += __shfl_xor(v, 8);
    if (c == 0) rsum[16 * wvi + quad * 4 + r] = v;
  }
  __syncthreads();  // B2: Asm, rsum, zpre visible

  // den[t] = max(rowsum + Q[t].z_pre, 1e-6)
  if (tid < 64) {
    float s = rsum[tid];
    int t7 = tid & 7;
#pragma unroll
    for (int kg = 0; kg < 8; kg++) {
      bf16x8 qv = *(const bf16x8*)(Qs + tid * 64 + ((kg ^ t7) << 3));
#pragma unroll
      for (int u = 0; u < 8; u++) s += (float)qv[u] * zpre[kg * 8 + u];
    }
    den[tid] = fmaxf(s, 1e-6f);
  }

  // O = Q.S_pre + A.V
  f32x4 oacc[4] = {};
#pragma unroll
  for (int ks = 0; ks < 2; ks++) {
    int ar = 16 * wvi + c;
    bf16x8 aq = *(const bf16x8*)(Qs + ar * 64 + (((ks * 4 + quad) ^ (c & 7)) << 3));
    bf16x8 aa = *(const bf16x8*)(Asm + ar * 64 + sw_t(ar, ks * 4 + quad));
#pragma unroll
    for (int j = 0; j < 4; j++) {
      int br = 16 * j + c;
      bf16x8 bs = *(const bf16x8*)(Spre + br * 64 + sw_t(br, ks * 4 + quad));
      bf16x8 bv = *(const bf16x8*)(Vt + br * 64 + sw_t(br, ks * 4 + quad));
      oacc[j] = __builtin_amdgcn_mfma_f32_16x16x32_bf16(aq, bs, oacc[j], 0, 0, 0);
      oacc[j] = __builtin_amdgcn_mfma_f32_16x16x32_bf16(aa, bv, oacc[j], 0, 0, 0);
    }
  }
  __syncthreads();  // B3: den visible; Qs/Ks region dead -> repack scratch

  // O repack (stride 76) + vector store
  {
    bf16* shr = SH;   // 64*76 = 4864 elems, overlays Qs/Ks
#pragma unroll
    for (int r = 0; r < 4; r++) {
      int t = 16 * wvi + quad * 4 + r;
      float rd = 1.f / den[t];
#pragma unroll
      for (int j = 0; j < 4; j++)
        shr[t * 76 + 16 * j + c] = (bf16)(oacc[j][r] * rd);
    }
    __syncthreads();
    int row = tid >> 2, col0 = (tid & 3) * 16;
    bf16x8 v0 = *(const bf16x8*)(shr + row * 76 + col0);
    bf16x8 v1 = *(const bf16x8*)(shr + row * 76 + col0 + 8);
    bf16* od = O + (size_t)(rowbase + row) * 512 + h * 64 + col0;
    *(bf16x8*)od = v0;
    *(bf16x8*)(od + 8) = v1;
  }
}

extern "C" void kernel_launch(void* const* d_in, const int* in_sizes, int n_in,
                              void* d_out, int out_size, void* d_ws, size_t ws_size,
                              hipStream_t stream) {
  const float* x  = (const float*)d_in[0];
  const float* wq = (const float*)d_in[1];
  const float* wk = (const float*)d_in[2];
  const float* wv = (const float*)d_in[3];
  const float* wo = (const float*)d_in[4];
  float* out = (float*)d_out;

  char* p = (char*)d_ws;
  bf16* wqkv_b = (bf16*)p; p += (size_t)3 * DMODEL * DMODEL * 2;
  bf16* wo_b   = (bf16*)p; p += (size_t)DMODEL * DMODEL * 2;
  bf16* Qb     = (bf16*)p; p += (size_t)MROWS * 512 * 2;
  bf16* Kb     = (bf16*)p; p += (size_t)MROWS * 512 * 2;
  bf16* Vb     = (bf16*)p; p += (size_t)MROWS * 512 * 2;
  bf16* Ob     = (bf16*)p; p += (size_t)MROWS * 512 * 2;
  bf16* KVs    = (bf16*)p; p += (size_t)BH * NCHUNK * DHEAD * DVAL * 2;
  float* zs    = (float*)p; p += (size_t)BH * NCHUNK * DHEAD * 4;

  k_convert<<<256, 256, 0, stream>>>(wq, wk, wv, wo, wqkv_b, wo_b);
  k_gemm_qkv<<<dim3(MROWS / 64, (3 * DMODEL) / 128), 256, 0, stream>>>(
      x, wqkv_b, Qb, Kb, Vb);
  k_state<<<dim3(NCHUNK, BH), 256, 0, stream>>>(Kb, Vb, KVs, zs);
  k_attn<<<512, 256, 0, stream>>>(Qb, Kb, Vb, KVs, zs, Ob);
  k_gemm_out<<<dim3(MROWS / 64, DMODEL / 64), 256, 0, stream>>>(Ob, wo_b, out);
}